// Round 3
// baseline (385.421 us; speedup 1.0000x reference)
//
#include <hip/hip_runtime.h>
#include <hip/hip_bf16.h>
#include <math.h>

// Problem constants
#define N_ 256
#define C_ 256
#define V_ 25
#define T_ 20
#define C4_ 64
#define O_ 256
#define VT_ 500
#define EPS_ 1e-5f

typedef unsigned short ushort_t;
typedef unsigned short us4 __attribute__((ext_vector_type(4)));
typedef short short8 __attribute__((ext_vector_type(8)));
typedef float f32x4 __attribute__((ext_vector_type(4)));

__device__ __forceinline__ float bf2f(ushort_t u) {
    unsigned int v = ((unsigned int)u) << 16;
    return __builtin_bit_cast(float, v);
}
__device__ __forceinline__ ushort_t f2bf(float f) {
    unsigned int u = __builtin_bit_cast(unsigned int, f);
    unsigned int r = u + 0x7fffu + ((u >> 16) & 1u);
    return (ushort_t)(r >> 16);
}

// ---------------- Kernel 1: fused pool + G branch + L branch + x->bf16 convert ----------------
// grid: 257 blocks. Blocks 0..255: one per n. Block 256: Wc2 fp32->bf16 prep.
__global__ __launch_bounds__(256) void k_front(const float* __restrict__ x,
                                               const float* __restrict__ Wg1,
                                               const float* __restrict__ Wg2,
                                               const float* __restrict__ Wl1,
                                               const float* __restrict__ Wl2,
                                               const float* __restrict__ Wc2,
                                               const float* __restrict__ bng,
                                               const float* __restrict__ bnl,
                                               float* __restrict__ kern,
                                               float* __restrict__ l2out,
                                               ushort_t* __restrict__ xbf,
                                               ushort_t* __restrict__ wbf) {
    int tid = threadIdx.x;
    if (blockIdx.x == 256) {
        // Wc2 -> bf16 (O*C = 65536 elems, 16384 vec4)
        const f32x4* src = (const f32x4*)Wc2;
        us4* dst = (us4*)wbf;
        for (int i = tid; i < 16384; i += 256) {
            f32x4 v = src[i];
            us4 o; o.x = f2bf(v.x); o.y = f2bf(v.y); o.z = f2bf(v.z); o.w = f2bf(v.w);
            dst[i] = o;
        }
        return;
    }

    __shared__ float pp[C_][22];   // pooled with t zero-pad (index t+1)
    __shared__ float wg1[800];
    __shared__ float wg2[120];
    __shared__ float sg[40], bg[40];
    __shared__ float ls[C4_][20];
    __shared__ float sl[C4_], bl[C4_];

    int n = blockIdx.x;
    const float* xn = x + n * (C_ * V_ * T_);

    // weights -> LDS (independent of pool)
    for (int i = tid; i < 800; i += 256) wg1[i] = Wg1[i];
    if (tid < 120) wg2[tid] = Wg2[tid];
    if (tid < 40) {
        float g = bng[tid], b = bng[40 + tid];
        float m = bng[80 + tid], v = bng[120 + tid];
        float s = g * rsqrtf(v + EPS_);
        sg[tid] = s; bg[tid] = b - m * s;
    }
    if (tid < C4_) {
        float g = bnl[tid], b = bnl[64 + tid];
        float m = bnl[128 + tid], v = bnl[192 + tid];
        float s = g * rsqrtf(v + EPS_);
        sl[tid] = s; bl[tid] = b - m * s;
    }
    // pool: pp[c][t+1] = mean_v x[n,c,v,t]; coalesced scalar pattern (lanes span t then c)
    for (int i = tid; i < C_ * T_; i += 256) {
        int c = i / T_, t = i % T_;
        const float* p = xn + c * (V_ * T_) + t;
        float s = 0.f;
#pragma unroll
        for (int v = 0; v < V_; ++v) s += p[v * T_];
        pp[c][t + 1] = s * (1.0f / V_);
    }
    pp[tid][0] = 0.f; pp[tid][21] = 0.f;
    __syncthreads();

    // ---- G branch: thread = c ----
    {
        int c = tid;
        float p[20];
#pragma unroll
        for (int t = 0; t < 20; ++t) p[t] = pp[c][t + 1];
        float l0 = 0.f, l1 = 0.f, l2 = 0.f;
#pragma unroll 4
        for (int j = 0; j < 40; ++j) {
            float h = 0.f;
#pragma unroll
            for (int t = 0; t < 20; ++t) h = fmaf(wg1[j * 20 + t], p[t], h);
            h = fmaxf(fmaf(h, sg[j], bg[j]), 0.f);
            l0 = fmaf(wg2[j], h, l0);
            l1 = fmaf(wg2[40 + j], h, l1);
            l2 = fmaf(wg2[80 + j], h, l2);
        }
        float mx = fmaxf(l0, fmaxf(l1, l2));
        float e0 = __expf(l0 - mx), e1 = __expf(l1 - mx), e2 = __expf(l2 - mx);
        float inv = 1.f / (e0 + e1 + e2);
        float* kp = kern + (n * C_ + c) * 3;
        kp[0] = e0 * inv; kp[1] = e1 * inv; kp[2] = e2 * inv;
    }

    // ---- L branch conv1: thread = (c4, t-group) ----
    {
        int c4 = tid >> 2;
        int t0 = (tid & 3) * 5;
        float acc0 = 0.f, acc1 = 0.f, acc2 = 0.f, acc3 = 0.f, acc4 = 0.f;
        const float* w = Wl1 + c4 * (C_ * 3);
        for (int c = 0; c < C_; ++c) {
            float w0 = w[c * 3 + 0];
            float w1 = w[c * 3 + 1];
            float w2 = w[c * 3 + 2];
            float a0 = pp[c][t0 + 0], a1 = pp[c][t0 + 1], a2 = pp[c][t0 + 2];
            float a3 = pp[c][t0 + 3], a4 = pp[c][t0 + 4], a5 = pp[c][t0 + 5];
            float a6 = pp[c][t0 + 6];
            acc0 = fmaf(w0, a0, fmaf(w1, a1, fmaf(w2, a2, acc0)));
            acc1 = fmaf(w0, a1, fmaf(w1, a2, fmaf(w2, a3, acc1)));
            acc2 = fmaf(w0, a2, fmaf(w1, a3, fmaf(w2, a4, acc2)));
            acc3 = fmaf(w0, a3, fmaf(w1, a4, fmaf(w2, a5, acc3)));
            acc4 = fmaf(w0, a4, fmaf(w1, a5, fmaf(w2, a6, acc4)));
        }
        float s = sl[c4], b = bl[c4];
        ls[c4][t0 + 0] = fmaxf(fmaf(acc0, s, b), 0.f);
        ls[c4][t0 + 1] = fmaxf(fmaf(acc1, s, b), 0.f);
        ls[c4][t0 + 2] = fmaxf(fmaf(acc2, s, b), 0.f);
        ls[c4][t0 + 3] = fmaxf(fmaf(acc3, s, b), 0.f);
        ls[c4][t0 + 4] = fmaxf(fmaf(acc4, s, b), 0.f);
    }
    __syncthreads();

    // ---- L branch conv2 + sigmoid: thread = c ----
    {
        int c = tid;
        float acc[20];
#pragma unroll
        for (int t = 0; t < 20; ++t) acc[t] = 0.f;
        const float* w = Wl2 + c * C4_;
        for (int c4 = 0; c4 < C4_; ++c4) {
            float wv = w[c4];
#pragma unroll
            for (int t = 0; t < 20; ++t) acc[t] = fmaf(wv, ls[c4][t], acc[t]);
        }
        float* o = l2out + n * (C_ * T_) + c * T_;
#pragma unroll
        for (int t = 0; t < 20; ++t) o[t] = 1.f / (1.f + __expf(-acc[t]));
    }

    // ---- convert x slab -> bf16 (coalesced; x slab is L2/L3-warm from pooling) ----
    {
        const f32x4* src = (const f32x4*)xn;
        us4* dst = (us4*)(xbf + n * (C_ * V_ * T_));
        for (int i = tid; i < (C_ * V_ * T_) / 4; i += 256) {
            f32x4 v = src[i];
            us4 o; o.x = f2bf(v.x); o.y = f2bf(v.y); o.z = f2bf(v.z); o.w = f2bf(v.w);
            dst[i] = o;
        }
    }
}

// ---------------- Kernel 2: fused dynamic conv + bn1/relu + 1x1 conv (MFMA) + bn2/relu ----------------
#define YSTRIDE 264   // 256 + 8 pad shorts, keeps 16B alignment, breaks bank conflicts

__global__ __launch_bounds__(256, 2) void k_main(const ushort_t* __restrict__ xbf,
                                                 const ushort_t* __restrict__ wbf,
                                                 const float* __restrict__ bn1p,
                                                 const float* __restrict__ bn2p,
                                                 const float* __restrict__ kern,
                                                 const float* __restrict__ l2ws,
                                                 float* __restrict__ out) {
    __shared__ __align__(16) ushort_t yT[112 * YSTRIDE];  // [p_local][c] bf16
    __shared__ float s2t[O_], b2t[O_];
    int tid = threadIdx.x;
    int n = blockIdx.y;
    int vblk = blockIdx.x;       // 0..4, 5 v's per block

    // ---- staging: y[c, p] = relu(bn1(sum_k kern*(x^T + l2))) ----
    {
        int c = tid;
        float g1 = bn1p[c], be1 = bn1p[256 + c];
        float m1 = bn1p[512 + c], v1 = bn1p[768 + c];
        float s1 = g1 * rsqrtf(v1 + EPS_);
        float b1 = be1 - m1 * s1;
        float g2 = bn2p[c], be2 = bn2p[256 + c];
        float m2 = bn2p[512 + c], v2 = bn2p[768 + c];
        float s2 = g2 * rsqrtf(v2 + EPS_);
        s2t[c] = s2; b2t[c] = be2 - m2 * s2;

        const float* kp = kern + (n * C_ + c) * 3;
        float k0 = kp[0], k1 = kp[1], k2 = kp[2];
        float l2r[20];
        const f32x4* lp = (const f32x4*)(l2ws + (n * C_ + c) * T_);
#pragma unroll
        for (int q = 0; q < 5; ++q) {
            f32x4 v = lp[q];
            l2r[q*4+0] = v.x; l2r[q*4+1] = v.y; l2r[q*4+2] = v.z; l2r[q*4+3] = v.w;
        }
        const ushort_t* xp = xbf + ((n * C_ + c) * V_ + vblk * 5) * T_;
#pragma unroll
        for (int vl = 0; vl < 5; ++vl) {
            float a[22];
            a[0] = 0.f; a[21] = 0.f;
            const us4* xv = (const us4*)(xp + vl * T_);   // 8B aligned (offsets are x40B)
#pragma unroll
            for (int q = 0; q < 5; ++q) {
                us4 u = xv[q];
                a[q*4 + 1] = bf2f(u.x) + l2r[q*4 + 0];
                a[q*4 + 2] = bf2f(u.y) + l2r[q*4 + 1];
                a[q*4 + 3] = bf2f(u.z) + l2r[q*4 + 2];
                a[q*4 + 4] = bf2f(u.w) + l2r[q*4 + 3];
            }
            ushort_t* yrow = yT + (vl * 20) * YSTRIDE + c;
#pragma unroll
            for (int t = 0; t < 20; ++t) {
                float z = fmaf(k0, a[t], fmaf(k1, a[t + 1], k2 * a[t + 2]));
                float y = fmaxf(fmaf(z, s1, b1), 0.f);
                yrow[t * YSTRIDE] = f2bf(y);
            }
        }
    }
    // zero the 12 pad rows (100..111) so MFMA reads defined data
    for (int i = tid; i < 12 * YSTRIDE; i += 256) yT[100 * YSTRIDE + i] = 0;
    __syncthreads();

    // ---- MFMA: out[o, p] = relu(bn2(sum_c Wc2[o,c]*y[c,p])) ----
    int lane = tid & 63;
    int wave = tid >> 6;
    int mrow = lane & 15;
    int kof = (lane >> 4) * 8;
    int obase = wave * 64;

    f32x4 acc[4][7];
#pragma unroll
    for (int mt = 0; mt < 4; ++mt)
#pragma unroll
        for (int ct = 0; ct < 7; ++ct) acc[mt][ct] = (f32x4){0.f, 0.f, 0.f, 0.f};

#pragma unroll 2
    for (int kk = 0; kk < C_; kk += 32) {
        short8 af[4];
        short8 bfr[7];
#pragma unroll
        for (int mt = 0; mt < 4; ++mt)
            af[mt] = *(const short8*)(wbf + (obase + mt * 16 + mrow) * C_ + kk + kof);
#pragma unroll
        for (int ct = 0; ct < 7; ++ct)
            bfr[ct] = *(const short8*)(yT + (ct * 16 + mrow) * YSTRIDE + kk + kof);
#pragma unroll
        for (int mt = 0; mt < 4; ++mt)
#pragma unroll
            for (int ct = 0; ct < 7; ++ct)
                acc[mt][ct] = __builtin_amdgcn_mfma_f32_16x16x32_bf16(af[mt], bfr[ct], acc[mt][ct], 0, 0, 0);
    }

    // ---- epilogue: bn2 + relu, store fp32 ----
    int prow = (lane >> 4) * 4;
    float* outn = out + n * (O_ * VT_);
#pragma unroll
    for (int ct = 0; ct < 7; ++ct) {
        int pl = ct * 16 + (lane & 15);
        if (pl < 100) {
            int p = vblk * 100 + pl;
#pragma unroll
            for (int mt = 0; mt < 4; ++mt) {
#pragma unroll
                for (int r = 0; r < 4; ++r) {
                    int o = obase + mt * 16 + prow + r;
                    float val = fmaxf(fmaf(acc[mt][ct][r], s2t[o], b2t[o]), 0.f);
                    outn[o * VT_ + p] = val;
                }
            }
        }
    }
}

extern "C" void kernel_launch(void* const* d_in, const int* in_sizes, int n_in,
                              void* d_out, int out_size, void* d_ws, size_t ws_size,
                              hipStream_t stream) {
    const float* x   = (const float*)d_in[0];
    const float* Wg1 = (const float*)d_in[1];
    const float* Wg2 = (const float*)d_in[2];
    const float* Wl1 = (const float*)d_in[3];
    const float* Wl2 = (const float*)d_in[4];
    const float* Wc2 = (const float*)d_in[5];
    const float* bng = (const float*)d_in[6];
    const float* bnl = (const float*)d_in[7];
    const float* bn1p = (const float*)d_in[8];
    const float* bn2p = (const float*)d_in[9];
    float* out = (float*)d_out;

    float* ws = (float*)d_ws;
    float* kern  = ws;                                  // N*C*3   = 196608 floats
    float* l2ws  = ws + 196608;                         // N*C*T   = 1310720 floats
    ushort_t* wbf = (ushort_t*)(ws + 196608 + 1310720); // O*C     = 65536 shorts
    ushort_t* xbf = wbf + 65536;                        // N*C*V*T = 32768000 shorts

    k_front<<<dim3(257), dim3(256), 0, stream>>>(x, Wg1, Wg2, Wl1, Wl2, Wc2, bng, bnl,
                                                 kern, l2ws, xbf, wbf);
    k_main<<<dim3(5, N_), dim3(256), 0, stream>>>(xbf, wbf, bn1p, bn2p, kern, l2ws, out);
}

// Round 4
// 374.187 us; speedup vs baseline: 1.0300x; 1.0300x over previous
//
#include <hip/hip_runtime.h>
#include <hip/hip_bf16.h>
#include <math.h>

// Problem constants
#define N_ 256
#define C_ 256
#define V_ 25
#define T_ 20
#define C4_ 64
#define O_ 256
#define VT_ 500
#define EPS_ 1e-5f

typedef unsigned short ushort_t;
typedef unsigned short us4 __attribute__((ext_vector_type(4)));
typedef short short8 __attribute__((ext_vector_type(8)));
typedef float f32x4 __attribute__((ext_vector_type(4)));

__device__ __forceinline__ ushort_t f2bf(float f) {
    unsigned int u = __builtin_bit_cast(unsigned int, f);
    unsigned int r = u + 0x7fffu + ((u >> 16) & 1u);
    return (ushort_t)(r >> 16);
}

// ---------------- Kernel 1: Wc2 fp32 -> bf16 (must precede k_mega) ----------------
__global__ __launch_bounds__(256) void k_prep(const float* __restrict__ Wc2,
                                              ushort_t* __restrict__ wbf) {
    int i = blockIdx.x * 256 + threadIdx.x;     // vec4 index, 16384 total
    f32x4 v = ((const f32x4*)Wc2)[i];
    us4 o; o.x = f2bf(v.x); o.y = f2bf(v.y); o.z = f2bf(v.z); o.w = f2bf(v.w);
    ((us4*)wbf)[i] = o;
}

// ---------------- Kernel 2: mega — pool + G + L + dyn-conv + bn1 + MFMA 1x1 + bn2 ----------------
// One block per n. LDS 61184 B. Phase layout (union region 0..59136):
//   A/B: pp[256][22], wg1[800], wg2[120], sg[40], bg[40], ls[64][20], sl[64], bl[64]  (32160 B)
//   C:   yT bf16 [112][YSTRIDE]  (59136 B)  then  outs f32 [128][100]  (51200 B)
// Persistent: s2t/b2t at 59136..61184.
#define YSTRIDE 264

__global__ __launch_bounds__(256, 1) void k_mega(const float* __restrict__ x,
                                                 const ushort_t* __restrict__ wbf,
                                                 const float* __restrict__ Wg1,
                                                 const float* __restrict__ Wg2,
                                                 const float* __restrict__ Wl1,
                                                 const float* __restrict__ Wl2,
                                                 const float* __restrict__ bng,
                                                 const float* __restrict__ bnl,
                                                 const float* __restrict__ bn1p,
                                                 const float* __restrict__ bn2p,
                                                 float* __restrict__ out) {
    __shared__ __align__(16) char smem[61184];
    float (*pp)[22] = (float(*)[22])(smem);               // 22528
    float* wg1 = (float*)(smem + 22528);                  // 3200
    float* wg2 = (float*)(smem + 25728);                  // 480
    float* sg  = (float*)(smem + 26208);                  // 160
    float* bg  = (float*)(smem + 26368);                  // 160
    float (*ls)[20] = (float(*)[20])(smem + 26528);       // 5120
    float* sl  = (float*)(smem + 31648);                  // 256
    float* bl  = (float*)(smem + 31904);                  // 256 -> 32160
    ushort_t* yT = (ushort_t*)(smem);                     // 59136 (phase C)
    float* outs  = (float*)(smem);                        // 51200 (phase C epilogue)
    float* s2t = (float*)(smem + 59136);                  // 1024
    float* b2t = (float*)(smem + 60160);                  // 1024

    int tid = threadIdx.x;
    int n = blockIdx.x;
    const float* xn = x + n * (C_ * V_ * T_);

    // ---- small weights -> LDS (independent of pool) ----
    for (int i = tid; i < 800; i += 256) wg1[i] = Wg1[i];
    if (tid < 120) wg2[tid] = Wg2[tid];
    if (tid < 40) {
        float g = bng[tid], b = bng[40 + tid];
        float m = bng[80 + tid], v = bng[120 + tid];
        float s = g * rsqrtf(v + EPS_);
        sg[tid] = s; bg[tid] = b - m * s;
    }
    if (tid < C4_) {
        float g = bnl[tid], b = bnl[64 + tid];
        float m = bnl[128 + tid], v = bnl[192 + tid];
        float s = g * rsqrtf(v + EPS_);
        sl[tid] = s; bl[tid] = b - m * s;
    }

    // ---- Phase A: pool. thread owns 5 (c, t-quad) slots; 125 independent vec4 loads ----
    {
        f32x4 pacc[5];
        const float* pbase[5];
        int pc[5], ptq[5];
#pragma unroll
        for (int k = 0; k < 5; ++k) {
            int s = tid + 256 * k;              // 1280 slots = 256 c x 5 t-quads
            pc[k] = s / 5; ptq[k] = s % 5;
            pbase[k] = xn + pc[k] * (V_ * T_) + ptq[k] * 4;
            pacc[k] = (f32x4){0.f, 0.f, 0.f, 0.f};
        }
#pragma unroll 5
        for (int v = 0; v < V_; ++v) {
#pragma unroll
            for (int k = 0; k < 5; ++k)
                pacc[k] += *(const f32x4*)(pbase[k] + v * T_);
        }
#pragma unroll
        for (int k = 0; k < 5; ++k) {
            int c = pc[k], t1 = ptq[k] * 4 + 1;
            pp[c][t1 + 0] = pacc[k].x * 0.04f;
            pp[c][t1 + 1] = pacc[k].y * 0.04f;
            pp[c][t1 + 2] = pacc[k].z * 0.04f;
            pp[c][t1 + 3] = pacc[k].w * 0.04f;
        }
        pp[tid][0] = 0.f; pp[tid][21] = 0.f;
    }
    __syncthreads();

    // ---- Phase B1: G branch (thread = c), kern kept in registers ----
    float k0, k1, k2, s1, b1;
    {
        int c = tid;
        float p[20];
#pragma unroll
        for (int t = 0; t < 20; ++t) p[t] = pp[c][t + 1];
        float l0 = 0.f, l1 = 0.f, l2 = 0.f;
#pragma unroll 4
        for (int j = 0; j < 40; ++j) {
            float h = 0.f;
#pragma unroll
            for (int t = 0; t < 20; ++t) h = fmaf(wg1[j * 20 + t], p[t], h);
            h = fmaxf(fmaf(h, sg[j], bg[j]), 0.f);
            l0 = fmaf(wg2[j], h, l0);
            l1 = fmaf(wg2[40 + j], h, l1);
            l2 = fmaf(wg2[80 + j], h, l2);
        }
        float mx = fmaxf(l0, fmaxf(l1, l2));
        float e0 = __expf(l0 - mx), e1 = __expf(l1 - mx), e2 = __expf(l2 - mx);
        float inv = 1.f / (e0 + e1 + e2);
        k0 = e0 * inv; k1 = e1 * inv; k2 = e2 * inv;

        // bn1 (registers, own c) and bn2 (LDS, indexed by o later)
        float g1 = bn1p[c], be1 = bn1p[256 + c];
        float m1 = bn1p[512 + c], v1 = bn1p[768 + c];
        s1 = g1 * rsqrtf(v1 + EPS_);
        b1 = be1 - m1 * s1;
        float g2 = bn2p[c], be2 = bn2p[256 + c];
        float m2 = bn2p[512 + c], v2 = bn2p[768 + c];
        float s2 = g2 * rsqrtf(v2 + EPS_);
        s2t[c] = s2; b2t[c] = be2 - m2 * s2;
    }

    // ---- Phase B2: L conv1 (thread = (c4, t-group)) ----
    {
        int c4 = tid >> 2;
        int t0 = (tid & 3) * 5;
        float acc0 = 0.f, acc1 = 0.f, acc2 = 0.f, acc3 = 0.f, acc4 = 0.f;
        const float* w = Wl1 + c4 * (C_ * 3);
#pragma unroll 8
        for (int c = 0; c < C_; ++c) {
            float w0 = w[c * 3 + 0];
            float w1 = w[c * 3 + 1];
            float w2 = w[c * 3 + 2];
            float a0 = pp[c][t0 + 0], a1 = pp[c][t0 + 1], a2 = pp[c][t0 + 2];
            float a3 = pp[c][t0 + 3], a4 = pp[c][t0 + 4], a5 = pp[c][t0 + 5];
            float a6 = pp[c][t0 + 6];
            acc0 = fmaf(w0, a0, fmaf(w1, a1, fmaf(w2, a2, acc0)));
            acc1 = fmaf(w0, a1, fmaf(w1, a2, fmaf(w2, a3, acc1)));
            acc2 = fmaf(w0, a2, fmaf(w1, a3, fmaf(w2, a4, acc2)));
            acc3 = fmaf(w0, a3, fmaf(w1, a4, fmaf(w2, a5, acc3)));
            acc4 = fmaf(w0, a4, fmaf(w1, a5, fmaf(w2, a6, acc4)));
        }
        float s = sl[c4], b = bl[c4];
        ls[c4][t0 + 0] = fmaxf(fmaf(acc0, s, b), 0.f);
        ls[c4][t0 + 1] = fmaxf(fmaf(acc1, s, b), 0.f);
        ls[c4][t0 + 2] = fmaxf(fmaf(acc2, s, b), 0.f);
        ls[c4][t0 + 3] = fmaxf(fmaf(acc3, s, b), 0.f);
        ls[c4][t0 + 4] = fmaxf(fmaf(acc4, s, b), 0.f);
    }
    __syncthreads();

    // ---- Phase B3: L conv2 + sigmoid (thread = c), result kept in registers ----
    float l2r[20];
    {
        int c = tid;
#pragma unroll
        for (int t = 0; t < 20; ++t) l2r[t] = 0.f;
        const float* w = Wl2 + c * C4_;
#pragma unroll 4
        for (int c4 = 0; c4 < C4_; ++c4) {
            float wv = w[c4];
#pragma unroll
            for (int t = 0; t < 20; ++t) l2r[t] = fmaf(wv, ls[c4][t], l2r[t]);
        }
#pragma unroll
        for (int t = 0; t < 20; ++t) l2r[t] = 1.f / (1.f + __expf(-l2r[t]));
    }
    __syncthreads();   // pp/wg1/ls dead; union region becomes yT/outs

    // ---- Phase C: per v-block: stage yT -> MFMA -> coalesced epilogue ----
    int lane = tid & 63;
    int wave = tid >> 6;
    int mrow = lane & 15;
    int kof = (lane >> 4) * 8;
    int prow = (lane >> 4) * 4;
    int obase = wave * 64;
    float* outn = out + n * (O_ * VT_);

    for (int vblk = 0; vblk < 5; ++vblk) {
        // staging: y[c, p] = relu(bn1(sum_k kern*(x^T + l2)))  [thread = c]
        {
            int c = tid;
            const float* xp = xn + (c * V_ + vblk * 5) * T_;
#pragma unroll
            for (int vl = 0; vl < 5; ++vl) {
                float a[22];
                a[0] = 0.f; a[21] = 0.f;
                const f32x4* xv = (const f32x4*)(xp + vl * T_);
#pragma unroll
                for (int q = 0; q < 5; ++q) {
                    f32x4 u = xv[q];
                    a[q*4 + 1] = u.x + l2r[q*4 + 0];
                    a[q*4 + 2] = u.y + l2r[q*4 + 1];
                    a[q*4 + 3] = u.z + l2r[q*4 + 2];
                    a[q*4 + 4] = u.w + l2r[q*4 + 3];
                }
                ushort_t* yrow = yT + (vl * 20) * YSTRIDE + c;
#pragma unroll
                for (int t = 0; t < 20; ++t) {
                    float z = fmaf(k0, a[t], fmaf(k1, a[t + 1], k2 * a[t + 2]));
                    float y = fmaxf(fmaf(z, s1, b1), 0.f);
                    yrow[t * YSTRIDE] = f2bf(y);
                }
            }
        }
        // zero guard rows 100..111
        for (int i = tid; i < 12 * YSTRIDE; i += 256) yT[100 * YSTRIDE + i] = 0;
        __syncthreads();

        // MFMA: full K = 256
        f32x4 acc[4][7];
#pragma unroll
        for (int mt = 0; mt < 4; ++mt)
#pragma unroll
            for (int ct = 0; ct < 7; ++ct) acc[mt][ct] = (f32x4){0.f, 0.f, 0.f, 0.f};

#pragma unroll 2
        for (int kk = 0; kk < C_; kk += 32) {
            short8 af[4];
            short8 bfr[7];
#pragma unroll
            for (int mt = 0; mt < 4; ++mt)
                af[mt] = *(const short8*)(wbf + (obase + mt * 16 + mrow) * C_ + kk + kof);
#pragma unroll
            for (int ct = 0; ct < 7; ++ct)
                bfr[ct] = *(const short8*)(yT + (ct * 16 + mrow) * YSTRIDE + kk + kof);
#pragma unroll
            for (int mt = 0; mt < 4; ++mt)
#pragma unroll
                for (int ct = 0; ct < 7; ++ct)
                    acc[mt][ct] = __builtin_amdgcn_mfma_f32_16x16x32_bf16(af[mt], bfr[ct], acc[mt][ct], 0, 0, 0);
        }
        __syncthreads();   // all waves done reading yT; region becomes outs

        // epilogue: 2 passes x 2 o-tiles; bn2+relu into LDS, then coalesced f32x4 stores
#pragma unroll
        for (int P = 0; P < 2; ++P) {
#pragma unroll
            for (int mtl = 0; mtl < 2; ++mtl) {
                int mt = 2 * P + mtl;
#pragma unroll
                for (int ct = 0; ct < 7; ++ct) {
                    int pl = ct * 16 + mrow;
                    if (pl < 100) {
#pragma unroll
                        for (int r = 0; r < 4; ++r) {
                            int og = obase + mt * 16 + prow + r;
                            int oo = wave * 32 + mtl * 16 + prow + r;
                            outs[oo * 100 + pl] =
                                fmaxf(fmaf(acc[mt][ct][r], s2t[og], b2t[og]), 0.f);
                        }
                    }
                }
            }
            __syncthreads();
            for (int i = tid; i < 3200; i += 256) {
                int oo = i / 25, col = i % 25;
                int og = (oo >> 5) * 64 + P * 32 + (oo & 31);
                *(f32x4*)(outn + og * VT_ + vblk * 100 + col * 4) = ((const f32x4*)outs)[i];
            }
            __syncthreads();
        }
    }
}

extern "C" void kernel_launch(void* const* d_in, const int* in_sizes, int n_in,
                              void* d_out, int out_size, void* d_ws, size_t ws_size,
                              hipStream_t stream) {
    const float* x   = (const float*)d_in[0];
    const float* Wg1 = (const float*)d_in[1];
    const float* Wg2 = (const float*)d_in[2];
    const float* Wl1 = (const float*)d_in[3];
    const float* Wl2 = (const float*)d_in[4];
    const float* Wc2 = (const float*)d_in[5];
    const float* bng = (const float*)d_in[6];
    const float* bnl = (const float*)d_in[7];
    const float* bn1p = (const float*)d_in[8];
    const float* bn2p = (const float*)d_in[9];
    float* out = (float*)d_out;

    ushort_t* wbf = (ushort_t*)d_ws;   // O*C bf16 = 128 KB

    k_prep<<<dim3(64), dim3(256), 0, stream>>>(Wc2, wbf);
    k_mega<<<dim3(N_), dim3(256), 0, stream>>>(x, wbf, Wg1, Wg2, Wl1, Wl2,
                                               bng, bnl, bn1p, bn2p, out);
}

// Round 5
// 364.775 us; speedup vs baseline: 1.0566x; 1.0258x over previous
//
#include <hip/hip_runtime.h>
#include <hip/hip_bf16.h>
#include <math.h>

// Problem constants
#define N_ 256
#define C_ 256
#define V_ 25
#define T_ 20
#define C4_ 64
#define O_ 256
#define VT_ 500
#define EPS_ 1e-5f

typedef unsigned short ushort_t;
typedef unsigned short us4 __attribute__((ext_vector_type(4)));
typedef short short8 __attribute__((ext_vector_type(8)));
typedef float f32x4 __attribute__((ext_vector_type(4)));

__device__ __forceinline__ float bf2f(ushort_t u) {
    unsigned int v = ((unsigned int)u) << 16;
    return __builtin_bit_cast(float, v);
}
__device__ __forceinline__ ushort_t f2bf(float f) {
    unsigned int u = __builtin_bit_cast(unsigned int, f);
    unsigned int r = u + 0x7fffu + ((u >> 16) & 1u);
    return (ushort_t)(r >> 16);
}

// ---------------- Kernel 1: pool (coalesced) + Wc2->bf16 prep ----------------
// Blocks 0..8191: 8 nc-rows each. Blocks 8192..8255: Wc2 convert.
__global__ __launch_bounds__(256) void k_pool(const float* __restrict__ x,
                                              float* __restrict__ pooled,
                                              const float* __restrict__ Wc2,
                                              ushort_t* __restrict__ wbf) {
    int tid = threadIdx.x;
    if (blockIdx.x >= 8192) {
        int i = (blockIdx.x - 8192) * 256 + tid;     // vec4 index, 16384 total
        f32x4 v = ((const f32x4*)Wc2)[i];
        us4 o; o.x = f2bf(v.x); o.y = f2bf(v.y); o.z = f2bf(v.z); o.w = f2bf(v.w);
        ((us4*)wbf)[i] = o;
        return;
    }
    __shared__ float xs[8][504];
    const f32x4* src = (const f32x4*)(x + (size_t)blockIdx.x * 8 * VT_);
    // 8 rows x 500 floats = 1000 vec4, fully coalesced (rows contiguous)
    for (int i = tid; i < 1000; i += 256) {
        int r = i / 125, cidx = (i % 125) * 4;
        *(f32x4*)&xs[r][cidx] = src[i];
    }
    __syncthreads();
    if (tid < 160) {
        int r = tid / 20, t = tid % 20;
        float s = 0.f;
#pragma unroll
        for (int v = 0; v < V_; ++v) s += xs[r][v * T_ + t];
        pooled[blockIdx.x * 160 + tid] = s * 0.04f;   // pooled[nc][t]
    }
}

// ---------------- Kernel 2: G + L branches per n ----------------
__global__ __launch_bounds__(256) void k_gl(const float* __restrict__ pooled,
                                            const float* __restrict__ Wg1,
                                            const float* __restrict__ Wg2,
                                            const float* __restrict__ Wl1,
                                            const float* __restrict__ Wl2,
                                            const float* __restrict__ bng,
                                            const float* __restrict__ bnl,
                                            float* __restrict__ kern,
                                            float* __restrict__ l2out) {
    __shared__ float pp[C_][22];
    __shared__ float wg1[800];
    __shared__ float wg2[120];
    __shared__ float sg[40], bg[40];
    __shared__ float ls[C4_][20];
    __shared__ float sl[C4_], bl[C4_];
    int tid = threadIdx.x;
    int n = blockIdx.x;

    for (int i = tid; i < 800; i += 256) wg1[i] = Wg1[i];
    if (tid < 120) wg2[tid] = Wg2[tid];
    if (tid < 40) {
        float g = bng[tid], b = bng[40 + tid];
        float m = bng[80 + tid], v = bng[120 + tid];
        float s = g * rsqrtf(v + EPS_);
        sg[tid] = s; bg[tid] = b - m * s;
    }
    if (tid < C4_) {
        float g = bnl[tid], b = bnl[64 + tid];
        float m = bnl[128 + tid], v = bnl[192 + tid];
        float s = g * rsqrtf(v + EPS_);
        sl[tid] = s; bl[tid] = b - m * s;
    }
    // pooled slab for this n: 256x20 = 1280 vec4, coalesced
    {
        const f32x4* pn = (const f32x4*)(pooled + n * (C_ * T_));
#pragma unroll
        for (int q = 0; q < 5; ++q) {
            int id = q * 256 + tid;
            int c = id / 5, qq = id % 5;
            f32x4 v = pn[id];
            pp[c][qq * 4 + 1] = v.x; pp[c][qq * 4 + 2] = v.y;
            pp[c][qq * 4 + 3] = v.z; pp[c][qq * 4 + 4] = v.w;
        }
        pp[tid][0] = 0.f; pp[tid][21] = 0.f;
    }
    __syncthreads();

    // G branch (thread = c)
    {
        int c = tid;
        float p[20];
#pragma unroll
        for (int t = 0; t < 20; ++t) p[t] = pp[c][t + 1];
        float l0 = 0.f, l1 = 0.f, l2 = 0.f;
#pragma unroll 4
        for (int j = 0; j < 40; ++j) {
            float h = 0.f;
#pragma unroll
            for (int t = 0; t < 20; ++t) h = fmaf(wg1[j * 20 + t], p[t], h);
            h = fmaxf(fmaf(h, sg[j], bg[j]), 0.f);
            l0 = fmaf(wg2[j], h, l0);
            l1 = fmaf(wg2[40 + j], h, l1);
            l2 = fmaf(wg2[80 + j], h, l2);
        }
        float mx = fmaxf(l0, fmaxf(l1, l2));
        float e0 = __expf(l0 - mx), e1 = __expf(l1 - mx), e2 = __expf(l2 - mx);
        float inv = 1.f / (e0 + e1 + e2);
        float* kp = kern + (n * C_ + c) * 3;
        kp[0] = e0 * inv; kp[1] = e1 * inv; kp[2] = e2 * inv;
    }

    // L conv1 (thread = (c4, t-group))
    {
        int c4 = tid >> 2;
        int t0 = (tid & 3) * 5;
        float acc0 = 0.f, acc1 = 0.f, acc2 = 0.f, acc3 = 0.f, acc4 = 0.f;
        const float* w = Wl1 + c4 * (C_ * 3);
#pragma unroll 8
        for (int c = 0; c < C_; ++c) {
            float w0 = w[c * 3 + 0];
            float w1 = w[c * 3 + 1];
            float w2 = w[c * 3 + 2];
            float a0 = pp[c][t0 + 0], a1 = pp[c][t0 + 1], a2 = pp[c][t0 + 2];
            float a3 = pp[c][t0 + 3], a4 = pp[c][t0 + 4], a5 = pp[c][t0 + 5];
            float a6 = pp[c][t0 + 6];
            acc0 = fmaf(w0, a0, fmaf(w1, a1, fmaf(w2, a2, acc0)));
            acc1 = fmaf(w0, a1, fmaf(w1, a2, fmaf(w2, a3, acc1)));
            acc2 = fmaf(w0, a2, fmaf(w1, a3, fmaf(w2, a4, acc2)));
            acc3 = fmaf(w0, a3, fmaf(w1, a4, fmaf(w2, a5, acc3)));
            acc4 = fmaf(w0, a4, fmaf(w1, a5, fmaf(w2, a6, acc4)));
        }
        float s = sl[c4], b = bl[c4];
        ls[c4][t0 + 0] = fmaxf(fmaf(acc0, s, b), 0.f);
        ls[c4][t0 + 1] = fmaxf(fmaf(acc1, s, b), 0.f);
        ls[c4][t0 + 2] = fmaxf(fmaf(acc2, s, b), 0.f);
        ls[c4][t0 + 3] = fmaxf(fmaf(acc3, s, b), 0.f);
        ls[c4][t0 + 4] = fmaxf(fmaf(acc4, s, b), 0.f);
    }
    __syncthreads();

    // L conv2 + sigmoid (thread = c)
    {
        int c = tid;
        float acc[20];
#pragma unroll
        for (int t = 0; t < 20; ++t) acc[t] = 0.f;
        const float* w = Wl2 + c * C4_;
#pragma unroll 4
        for (int c4 = 0; c4 < C4_; ++c4) {
            float wv = w[c4];
#pragma unroll
            for (int t = 0; t < 20; ++t) acc[t] = fmaf(wv, ls[c4][t], acc[t]);
        }
        f32x4* o = (f32x4*)(l2out + (n * C_ + c) * T_);
#pragma unroll
        for (int q = 0; q < 5; ++q) {
            f32x4 v;
            v.x = 1.f / (1.f + __expf(-acc[q*4+0]));
            v.y = 1.f / (1.f + __expf(-acc[q*4+1]));
            v.z = 1.f / (1.f + __expf(-acc[q*4+2]));
            v.w = 1.f / (1.f + __expf(-acc[q*4+3]));
            o[q] = v;
        }
    }
}

// ---------------- Kernel 3: dyn-conv + bn1 + MFMA 1x1 + bn2, grid (5, N) ----------------
#define YSTRIDE 264

__global__ __launch_bounds__(256, 2) void k_main(const float* __restrict__ x,
                                                 const ushort_t* __restrict__ wbf,
                                                 const float* __restrict__ bn1p,
                                                 const float* __restrict__ bn2p,
                                                 const float* __restrict__ kern,
                                                 const float* __restrict__ l2g,
                                                 float* __restrict__ out) {
    __shared__ __align__(16) char smem[61184];
    ushort_t* yT  = (ushort_t*)smem;          // 112 x YSTRIDE bf16 = 59136
    float*    outs = (float*)smem;            // 128 x 100 f32 = 51200 (epilogue overlay)
    float* s2t = (float*)(smem + 59136);      // 1024
    float* b2t = (float*)(smem + 60160);      // 1024

    int tid = threadIdx.x;
    int n = blockIdx.y;
    int vblk = blockIdx.x;
    const float* xn = x + n * (C_ * V_ * T_);

    // per-c params (thread = c)
    float s1, b1, k0, k1, k2, l2r[20];
    {
        int c = tid;
        float g1 = bn1p[c], be1 = bn1p[256 + c];
        float m1 = bn1p[512 + c], v1 = bn1p[768 + c];
        s1 = g1 * rsqrtf(v1 + EPS_);
        b1 = be1 - m1 * s1;
        float g2 = bn2p[c], be2 = bn2p[256 + c];
        float m2 = bn2p[512 + c], v2 = bn2p[768 + c];
        float s2 = g2 * rsqrtf(v2 + EPS_);
        s2t[c] = s2; b2t[c] = be2 - m2 * s2;
        const float* kp = kern + (n * C_ + c) * 3;
        k0 = kp[0]; k1 = kp[1]; k2 = kp[2];
        const f32x4* lp = (const f32x4*)(l2g + (n * C_ + c) * T_);
#pragma unroll
        for (int q = 0; q < 5; ++q) {
            f32x4 v = lp[q];
            l2r[q*4+0] = v.x; l2r[q*4+1] = v.y; l2r[q*4+2] = v.z; l2r[q*4+3] = v.w;
        }
    }

    // ---- staging: per vl, cooperative coalesced slab load -> LDS(bf16) -> conv -> yT ----
    for (int vl = 0; vl < 5; ++vl) {
        ushort_t* xs = yT + (vl * 20) * YSTRIDE;   // xs[c][20], aliases this vl's future yT rows
        // 1280 f32x4: id -> (c = id/5, qq = id%5); 5 consecutive lanes cover one c's 80B
#pragma unroll
        for (int q = 0; q < 5; ++q) {
            int id = q * 256 + tid;
            int c = id / 5, qq = id % 5;
            f32x4 v = *(const f32x4*)(xn + c * VT_ + vblk * 100 + vl * 20 + qq * 4);
            us4 o; o.x = f2bf(v.x); o.y = f2bf(v.y); o.z = f2bf(v.z); o.w = f2bf(v.w);
            *(us4*)(xs + c * 20 + qq * 4) = o;
        }
        __syncthreads();
        // read own row into regs
        float a[22];
        a[0] = 0.f; a[21] = 0.f;
        {
            const ushort_t* xrow = xs + tid * 20;
#pragma unroll
            for (int qq = 0; qq < 5; ++qq) {
                us4 u = *(const us4*)(xrow + qq * 4);
                a[qq*4 + 1] = bf2f(u.x) + l2r[qq*4 + 0];
                a[qq*4 + 2] = bf2f(u.y) + l2r[qq*4 + 1];
                a[qq*4 + 3] = bf2f(u.z) + l2r[qq*4 + 2];
                a[qq*4 + 4] = bf2f(u.w) + l2r[qq*4 + 3];
            }
        }
        __syncthreads();   // all xs reads done before overwriting region as yT
        {
            ushort_t* yrow = yT + (vl * 20) * YSTRIDE + tid;
#pragma unroll
            for (int t = 0; t < 20; ++t) {
                float z = fmaf(k0, a[t], fmaf(k1, a[t + 1], k2 * a[t + 2]));
                yrow[t * YSTRIDE] = f2bf(fmaxf(fmaf(z, s1, b1), 0.f));
            }
        }
    }
    // zero guard rows 100..111
    for (int i = tid; i < 12 * YSTRIDE; i += 256) yT[100 * YSTRIDE + i] = 0;
    __syncthreads();

    // ---- MFMA: out[o,p] = sum_c Wc2[o,c] * y[c,p] ----
    int lane = tid & 63;
    int wave = tid >> 6;
    int mrow = lane & 15;
    int kof = (lane >> 4) * 8;
    int prow = (lane >> 4) * 4;
    int obase = wave * 64;

    f32x4 acc[4][7];
#pragma unroll
    for (int mt = 0; mt < 4; ++mt)
#pragma unroll
        for (int ct = 0; ct < 7; ++ct) acc[mt][ct] = (f32x4){0.f, 0.f, 0.f, 0.f};

#pragma unroll 2
    for (int kk = 0; kk < C_; kk += 32) {
        short8 af[4];
        short8 bfr[7];
#pragma unroll
        for (int mt = 0; mt < 4; ++mt)
            af[mt] = *(const short8*)(wbf + (obase + mt * 16 + mrow) * C_ + kk + kof);
#pragma unroll
        for (int ct = 0; ct < 7; ++ct)
            bfr[ct] = *(const short8*)(yT + (ct * 16 + mrow) * YSTRIDE + kk + kof);
#pragma unroll
        for (int mt = 0; mt < 4; ++mt)
#pragma unroll
            for (int ct = 0; ct < 7; ++ct)
                acc[mt][ct] = __builtin_amdgcn_mfma_f32_16x16x32_bf16(af[mt], bfr[ct], acc[mt][ct], 0, 0, 0);
    }
    __syncthreads();   // yT dead; region becomes outs

    // ---- epilogue: bn2+relu via LDS, coalesced f32x4 stores ----
    float* outn = out + n * (O_ * VT_);
#pragma unroll
    for (int P = 0; P < 2; ++P) {
#pragma unroll
        for (int mtl = 0; mtl < 2; ++mtl) {
            int mt = 2 * P + mtl;
#pragma unroll
            for (int ct = 0; ct < 7; ++ct) {
                int pl = ct * 16 + mrow;
                if (pl < 100) {
#pragma unroll
                    for (int r = 0; r < 4; ++r) {
                        int og = obase + mt * 16 + prow + r;
                        int oo = wave * 32 + mtl * 16 + prow + r;
                        outs[oo * 100 + pl] =
                            fmaxf(fmaf(acc[mt][ct][r], s2t[og], b2t[og]), 0.f);
                    }
                }
            }
        }
        __syncthreads();
        for (int i = tid; i < 3200; i += 256) {
            int oo = i / 25, col = i % 25;
            int og = (oo >> 5) * 64 + P * 32 + (oo & 31);
            *(f32x4*)(outn + og * VT_ + vblk * 100 + col * 4) = ((const f32x4*)outs)[i];
        }
        __syncthreads();
    }
}

extern "C" void kernel_launch(void* const* d_in, const int* in_sizes, int n_in,
                              void* d_out, int out_size, void* d_ws, size_t ws_size,
                              hipStream_t stream) {
    const float* x   = (const float*)d_in[0];
    const float* Wg1 = (const float*)d_in[1];
    const float* Wg2 = (const float*)d_in[2];
    const float* Wl1 = (const float*)d_in[3];
    const float* Wl2 = (const float*)d_in[4];
    const float* Wc2 = (const float*)d_in[5];
    const float* bng = (const float*)d_in[6];
    const float* bnl = (const float*)d_in[7];
    const float* bn1p = (const float*)d_in[8];
    const float* bn2p = (const float*)d_in[9];
    float* out = (float*)d_out;

    float* ws = (float*)d_ws;
    float* pooled = ws;                                  // N*C*T = 1310720 f
    float* kern   = ws + 1310720;                        // N*C*3 = 196608 f
    float* l2g    = ws + 1310720 + 196608;               // N*C*T = 1310720 f
    ushort_t* wbf = (ushort_t*)(ws + 1310720 + 196608 + 1310720);  // O*C bf16

    k_pool<<<dim3(8256), dim3(256), 0, stream>>>(x, pooled, Wc2, wbf);
    k_gl<<<dim3(N_), dim3(256), 0, stream>>>(pooled, Wg1, Wg2, Wl1, Wl2, bng, bnl, kern, l2g);
    k_main<<<dim3(5, N_), dim3(256), 0, stream>>>(x, wbf, bn1p, bn2p, kern, l2g, out);
}